// Round 4
// baseline (765.427 us; speedup 1.0000x reference)
//
#include <hip/hip_runtime.h>
#include <hip/hip_bf16.h>

#define D_MODEL 1024
#define D_FF    4096
#define N_EXPERTS 8
#define TOPK    2
#define T_TOK   4096
#define NPAIR   (T_TOK * TOPK)   // 8192
#define MT_MAX  32               // ceil(T_TOK / 128) worst case per expert
#define KSPLIT  2                // gemm2 split-K factor

typedef __attribute__((ext_vector_type(8))) short s8v;          // bf16x8 MFMA frag
typedef __attribute__((ext_vector_type(4))) float f4v;          // fp32x4 MFMA acc
typedef __attribute__((ext_vector_type(4))) unsigned short u16x4;
typedef __attribute__((ext_vector_type(8))) unsigned short u16x8;

__device__ __forceinline__ void async16(const void* g, void* l) {
    __builtin_amdgcn_global_load_lds(
        (const __attribute__((address_space(1))) void*)g,
        (__attribute__((address_space(3))) void*)l, 16, 0, 0);
}

// counted vmcnt wait: leaves newest N loads in flight (T4).
#define WAIT_VM(N) asm volatile("s_waitcnt vmcnt(" #N ")" ::: "memory")
#define CFENCE()   asm volatile("" ::: "memory")

__device__ __forceinline__ float gelu_tanh(float v) {
    float u = 0.7978845608028654f * (v + 0.044715f * v * v * v);
    float t = 1.0f - 2.0f / (1.0f + __expf(2.0f * u));
    return 0.5f * v * (1.0f + t);
}

__device__ __forceinline__ unsigned short f2bf(float f) {
    union { __hip_bfloat16 b; unsigned short u; } cv;
    cv.b = __float2bfloat16(f);
    return cv.u;
}

// ---------------------------------------------------------------- router (+x cast)
__global__ __launch_bounds__(256) void router_kernel(
    const float* __restrict__ x, const float* __restrict__ Wg,
    int* __restrict__ top_e, float* __restrict__ top_w,
    __hip_bfloat16* __restrict__ xb)
{
    int wave = threadIdx.x >> 6;
    int lane = threadIdx.x & 63;
    int t = blockIdx.x * 4 + wave;
    if (t >= T_TOK) return;

    float acc[8] = {0.f,0.f,0.f,0.f,0.f,0.f,0.f,0.f};
    const float* xr = x + (size_t)t * D_MODEL;
    unsigned short* xbr = (unsigned short*)xb + (size_t)t * D_MODEL;
    #pragma unroll
    for (int it = 0; it < 4; it++) {
        int d0 = it * 256 + lane * 4;
        float4 xv = *(const float4*)(xr + d0);
        unsigned short bfv[4] = {f2bf(xv.x), f2bf(xv.y), f2bf(xv.z), f2bf(xv.w)};
        *(u16x4*)(xbr + d0) = *(u16x4*)bfv;
        float xa[4] = {xv.x, xv.y, xv.z, xv.w};
        #pragma unroll
        for (int u = 0; u < 4; u++) {
            const float* wr = Wg + (size_t)(d0 + u) * N_EXPERTS;
            float4 w0 = *(const float4*)wr;
            float4 w1 = *(const float4*)(wr + 4);
            acc[0] += xa[u] * w0.x; acc[1] += xa[u] * w0.y;
            acc[2] += xa[u] * w0.z; acc[3] += xa[u] * w0.w;
            acc[4] += xa[u] * w1.x; acc[5] += xa[u] * w1.y;
            acc[6] += xa[u] * w1.z; acc[7] += xa[u] * w1.w;
        }
    }
    #pragma unroll
    for (int off = 32; off >= 1; off >>= 1) {
        #pragma unroll
        for (int e = 0; e < 8; e++) acc[e] += __shfl_xor(acc[e], off);
    }
    if (lane == 0) {
        float m = acc[0];
        #pragma unroll
        for (int e = 1; e < 8; e++) m = fmaxf(m, acc[e]);
        float p[8]; float s = 0.f;
        #pragma unroll
        for (int e = 0; e < 8; e++) { p[e] = expf(acc[e] - m); s += p[e]; }
        float inv = 1.f / s;
        #pragma unroll
        for (int e = 0; e < 8; e++) p[e] *= inv;
        int i0 = 0; float b0 = p[0];
        #pragma unroll
        for (int e = 1; e < 8; e++) if (p[e] > b0) { b0 = p[e]; i0 = e; }
        int i1 = -1; float b1 = -1.f;
        #pragma unroll
        for (int e = 0; e < 8; e++) if (e != i0 && p[e] > b1) { b1 = p[e]; i1 = e; }
        top_e[2*t]   = i0; top_w[2*t]   = b0;
        top_e[2*t+1] = i1; top_w[2*t+1] = b1;
    }
}

// ------------------------------------------- setup: histogram + offsets + scatter
__global__ __launch_bounds__(256) void setup_kernel(
    const int* __restrict__ top_e, int* __restrict__ offsets,
    int* __restrict__ pair_id)
{
    __shared__ int cnt[N_EXPERTS], base[N_EXPERTS], cur[N_EXPERTS];
    int tid = threadIdx.x;
    if (tid < N_EXPERTS) { cnt[tid] = 0; cur[tid] = 0; }
    __syncthreads();
    for (int i = tid; i < NPAIR; i += 256) atomicAdd(&cnt[top_e[i]], 1);
    __syncthreads();
    if (tid == 0) {
        int run = 0;
        #pragma unroll
        for (int e = 0; e < N_EXPERTS; e++) { base[e] = run; offsets[e] = run; run += cnt[e]; }
        offsets[N_EXPERTS] = run;
    }
    __syncthreads();
    for (int i = tid; i < NPAIR; i += 256) {
        int e = top_e[i];
        int pos = atomicAdd(&cur[e], 1);
        pair_id[base[e] + pos] = i;
    }
}

// ------------------------------------------------- transpose-cast W -> [E][N][K] bf16
__global__ __launch_bounds__(256) void transpose_cast_kernel(
    const float* __restrict__ src, __hip_bfloat16* __restrict__ dst, int R, int C)
{
    int e = blockIdx.z;
    src += (size_t)e * R * C;
    dst += (size_t)e * R * C;
    int b0 = blockIdx.x * 64;
    int a0 = blockIdx.y * 64;

    __shared__ float tile[64][65];
    int tid = threadIdx.x;
    int lr = tid >> 4;
    int lc = (tid & 15) * 4;
    #pragma unroll
    for (int rr = 0; rr < 4; rr++) {
        int r = lr + rr * 16;
        *(float4*)&tile[r][lc] = *(const float4*)(src + (size_t)(a0 + r) * C + b0 + lc);
    }
    __syncthreads();
    int oc = tid >> 3;
    int oj = (tid & 7) * 8;
    #pragma unroll
    for (int rr = 0; rr < 2; rr++) {
        int c = oc + rr * 32;
        unsigned short t[8];
        #pragma unroll
        for (int j = 0; j < 8; j++) t[j] = f2bf(tile[oj + j][c]);
        *(u16x8*)((unsigned short*)dst + (size_t)(b0 + c) * R + a0 + oj) = *(u16x8*)t;
    }
}

// ---------------------------------------------------------------- GEMM1 (MFMA)
// XCD-pinned flat grid: bid&7 = expert = XCD (8192 % 8 == 0, round-robin HW map).
// Slot order within expert is B-chunk-major: consecutive slots share (n0), so the
// concurrently-resident m-tile blocks on one XCD reuse the same B panel via L2.
// Inner loop identical to round 3 (128x128, BK=32, dbuf, counted vmcnt).
__global__ __launch_bounds__(256) void gemm1_mfma(
    const __hip_bfloat16* __restrict__ xb, const __hip_bfloat16* __restrict__ W1T,
    const float* __restrict__ b1,
    const int* __restrict__ offsets, const int* __restrict__ pair_id,
    __hip_bfloat16* __restrict__ h)
{
    int bid = blockIdx.x;            // 8 * 32(n) * 32(mt) = 8192
    int e   = bid & 7;               // expert -> XCD
    int s   = bid >> 3;
    int n_idx = s >> 5;              // 0..31 (B-chunk major)
    int mt    = s & 31;
    int off_e = offsets[e];
    int cnt   = offsets[e + 1] - off_e;
    int m0 = mt * 128;
    if (m0 >= cnt) return;
    int n0 = n_idx * 128;

    __shared__ __hip_bfloat16 As[2][128 * 32];
    __shared__ __hip_bfloat16 Bs[2][128 * 32];
    __shared__ int pid[128];

    int tid = threadIdx.x;
    if (tid < 128) {
        int r = m0 + tid; if (r >= cnt) r = cnt - 1;
        pid[tid] = pair_id[off_e + r];
    }
    __syncthreads();

    int lane = tid & 63, wid = tid >> 6;
    int c0 = tid, c1 = tid + 256;
    int r0 = ((c0 >> 6) << 4) | (c0 & 15), kb0 = (c0 >> 4) & 3;
    int r1 = ((c1 >> 6) << 4) | (c1 & 15), kb1 = (c1 >> 4) & 3;

    const __hip_bfloat16* gA0 = xb + (size_t)(pid[r0] >> 1) * D_MODEL + kb0 * 8;
    const __hip_bfloat16* gA1 = xb + (size_t)(pid[r1] >> 1) * D_MODEL + kb1 * 8;
    const __hip_bfloat16* WT  = W1T + (size_t)e * (D_MODEL * D_FF);
    const __hip_bfloat16* gB0 = WT + (size_t)(n0 + r0) * D_MODEL + kb0 * 8;
    const __hip_bfloat16* gB1 = WT + (size_t)(n0 + r1) * D_MODEL + kb1 * 8;

    int fm = lane & 15;
    int wm = (wid >> 1) * 64;
    int wn = (wid & 1) * 64;
    int rba = (wid >> 1) * 4;     // A region base (row blocks of 16)
    int rbb = (wid & 1) * 4;      // B region base

    f4v acc[4][4];
    #pragma unroll
    for (int i = 0; i < 4; i++)
        #pragma unroll
        for (int j = 0; j < 4; j++)
            acc[i][j] = (f4v){0.f, 0.f, 0.f, 0.f};

    const int NT = D_MODEL / 32;   // 32

    async16(gA0, As[0] + c0 * 8);
    async16(gA1, As[0] + c1 * 8);
    async16(gB0, Bs[0] + c0 * 8);
    async16(gB1, Bs[0] + c1 * 8);

    for (int t = 0; t + 1 < NT; ++t) {
        int cur = t & 1, nxt = cur ^ 1;
        int k1 = (t + 1) * 32;
        async16(gA0 + k1, As[nxt] + c0 * 8);
        async16(gA1 + k1, As[nxt] + c1 * 8);
        async16(gB0 + k1, Bs[nxt] + c0 * 8);
        async16(gB1 + k1, Bs[nxt] + c1 * 8);
        WAIT_VM(4);
        __builtin_amdgcn_s_barrier();
        CFENCE();
        s8v af[4], bfr[4];
        #pragma unroll
        for (int i = 0; i < 4; i++)
            af[i] = *(const s8v*)(As[cur] + (rba + i) * 512 + lane * 8);
        #pragma unroll
        for (int j = 0; j < 4; j++)
            bfr[j] = *(const s8v*)(Bs[cur] + (rbb + j) * 512 + lane * 8);
        #pragma unroll
        for (int i = 0; i < 4; i++)
            #pragma unroll
            for (int j = 0; j < 4; j++)
                acc[i][j] = __builtin_amdgcn_mfma_f32_16x16x32_bf16(af[i], bfr[j], acc[i][j], 0, 0, 0);
        CFENCE();
        __builtin_amdgcn_s_barrier();
    }
    {   // final tile
        int cur = (NT - 1) & 1;
        WAIT_VM(0);
        __builtin_amdgcn_s_barrier();
        CFENCE();
        s8v af[4], bfr[4];
        #pragma unroll
        for (int i = 0; i < 4; i++)
            af[i] = *(const s8v*)(As[cur] + (rba + i) * 512 + lane * 8);
        #pragma unroll
        for (int j = 0; j < 4; j++)
            bfr[j] = *(const s8v*)(Bs[cur] + (rbb + j) * 512 + lane * 8);
        #pragma unroll
        for (int i = 0; i < 4; i++)
            #pragma unroll
            for (int j = 0; j < 4; j++)
                acc[i][j] = __builtin_amdgcn_mfma_f32_16x16x32_bf16(af[i], bfr[j], acc[i][j], 0, 0, 0);
    }

    int rq = (lane >> 4) * 4;   // C/D: row = (lane>>4)*4 + reg, col = lane&15
    #pragma unroll
    for (int i = 0; i < 4; i++) {
        #pragma unroll
        for (int j = 0; j < 4; j++) {
            int n = n0 + wn + j * 16 + fm;
            float bias = b1[e * D_FF + n];
            #pragma unroll
            for (int r = 0; r < 4; r++) {
                int m = wm + i * 16 + rq + r;
                if (m0 + m < cnt) {
                    float v = acc[i][j][r] + bias;
                    h[(size_t)(off_e + m0 + m) * D_FF + n] = __float2bfloat16(gelu_tanh(v));
                }
            }
        }
    }
}

// ---------------------------------------------------------------- GEMM2 (MFMA, split-K)
// Same XCD pinning: bid&7 = expert. Slot order: (n_idx, split) major, mt minor,
// so concurrent blocks on the XCD share the (n0, split) B-chunk.
__global__ __launch_bounds__(256) void gemm2_mfma(
    const __hip_bfloat16* __restrict__ h, const __hip_bfloat16* __restrict__ W2T,
    const float* __restrict__ b2,
    const int* __restrict__ offsets, const int* __restrict__ pair_id,
    float* __restrict__ y0, float* __restrict__ y1)
{
    int bid = blockIdx.x;            // 8 * 8(n) * KSPLIT * 32(mt) = 4096
    int e   = bid & 7;               // expert -> XCD
    int s   = bid >> 3;
    int mt    = s & 31;
    int q     = s >> 5;              // n_idx*KSPLIT + split
    int split = q & (KSPLIT - 1);
    int n_idx = q / KSPLIT;
    int off_e = offsets[e];
    int cnt   = offsets[e + 1] - off_e;
    int m0 = mt * 128;
    if (m0 >= cnt) return;
    int n0 = n_idx * 128;

    __shared__ __hip_bfloat16 As[2][128 * 32];
    __shared__ __hip_bfloat16 Bs[2][128 * 32];
    __shared__ int pid[128];

    int tid = threadIdx.x;
    if (tid < 128) {
        int r = m0 + tid; if (r >= cnt) r = cnt - 1;
        pid[tid] = pair_id[off_e + r];
    }
    __syncthreads();

    int lane = tid & 63, wid = tid >> 6;
    int c0 = tid, c1 = tid + 256;
    int r0 = ((c0 >> 6) << 4) | (c0 & 15), kb0 = (c0 >> 4) & 3;
    int r1 = ((c1 >> 6) << 4) | (c1 & 15), kb1 = (c1 >> 4) & 3;
    int mr0 = m0 + r0; if (mr0 >= cnt) mr0 = cnt - 1;
    int mr1 = m0 + r1; if (mr1 >= cnt) mr1 = cnt - 1;

    const int KS = D_FF / KSPLIT;          // 2048
    int kbase = split * KS;

    const __hip_bfloat16* gA0 = h + (size_t)(off_e + mr0) * D_FF + kbase + kb0 * 8;
    const __hip_bfloat16* gA1 = h + (size_t)(off_e + mr1) * D_FF + kbase + kb1 * 8;
    const __hip_bfloat16* WT  = W2T + (size_t)e * (D_FF * D_MODEL);
    const __hip_bfloat16* gB0 = WT + (size_t)(n0 + r0) * D_FF + kbase + kb0 * 8;
    const __hip_bfloat16* gB1 = WT + (size_t)(n0 + r1) * D_FF + kbase + kb1 * 8;

    int fm = lane & 15;
    int wm = (wid >> 1) * 64;
    int wn = (wid & 1) * 64;
    int rba = (wid >> 1) * 4;
    int rbb = (wid & 1) * 4;

    f4v acc[4][4];
    #pragma unroll
    for (int i = 0; i < 4; i++)
        #pragma unroll
        for (int j = 0; j < 4; j++)
            acc[i][j] = (f4v){0.f, 0.f, 0.f, 0.f};

    const int NT = KS / 32;   // 64

    async16(gA0, As[0] + c0 * 8);
    async16(gA1, As[0] + c1 * 8);
    async16(gB0, Bs[0] + c0 * 8);
    async16(gB1, Bs[0] + c1 * 8);

    for (int t = 0; t + 1 < NT; ++t) {
        int cur = t & 1, nxt = cur ^ 1;
        int k1 = (t + 1) * 32;
        async16(gA0 + k1, As[nxt] + c0 * 8);
        async16(gA1 + k1, As[nxt] + c1 * 8);
        async16(gB0 + k1, Bs[nxt] + c0 * 8);
        async16(gB1 + k1, Bs[nxt] + c1 * 8);
        WAIT_VM(4);
        __builtin_amdgcn_s_barrier();
        CFENCE();
        s8v af[4], bfr[4];
        #pragma unroll
        for (int i = 0; i < 4; i++)
            af[i] = *(const s8v*)(As[cur] + (rba + i) * 512 + lane * 8);
        #pragma unroll
        for (int j = 0; j < 4; j++)
            bfr[j] = *(const s8v*)(Bs[cur] + (rbb + j) * 512 + lane * 8);
        #pragma unroll
        for (int i = 0; i < 4; i++)
            #pragma unroll
            for (int j = 0; j < 4; j++)
                acc[i][j] = __builtin_amdgcn_mfma_f32_16x16x32_bf16(af[i], bfr[j], acc[i][j], 0, 0, 0);
        CFENCE();
        __builtin_amdgcn_s_barrier();
    }
    {   // final tile
        int cur = (NT - 1) & 1;
        WAIT_VM(0);
        __builtin_amdgcn_s_barrier();
        CFENCE();
        s8v af[4], bfr[4];
        #pragma unroll
        for (int i = 0; i < 4; i++)
            af[i] = *(const s8v*)(As[cur] + (rba + i) * 512 + lane * 8);
        #pragma unroll
        for (int j = 0; j < 4; j++)
            bfr[j] = *(const s8v*)(Bs[cur] + (rbb + j) * 512 + lane * 8);
        #pragma unroll
        for (int i = 0; i < 4; i++)
            #pragma unroll
            for (int j = 0; j < 4; j++)
                acc[i][j] = __builtin_amdgcn_mfma_f32_16x16x32_bf16(af[i], bfr[j], acc[i][j], 0, 0, 0);
    }

    float* yo = split ? y1 : y0;
    int rq = (lane >> 4) * 4;
    #pragma unroll
    for (int i = 0; i < 4; i++) {
        #pragma unroll
        for (int j = 0; j < 4; j++) {
            int n = n0 + wn + j * 16 + fm;
            float bias = split ? 0.f : b2[e * D_MODEL + n];
            #pragma unroll
            for (int r = 0; r < 4; r++) {
                int m = wm + i * 16 + rq + r;
                if (m0 + m < cnt) {
                    int p = pid[m];
                    yo[(size_t)p * D_MODEL + n] = acc[i][j][r] + bias;
                }
            }
        }
    }
}

// ---------------------------------------------------------------- combine
__global__ __launch_bounds__(256) void combine_kernel(
    const float* __restrict__ y0, const float* __restrict__ y1,
    const float* __restrict__ top_w, float* __restrict__ out)
{
    int gid = blockIdx.x * blockDim.x + threadIdx.x;
    int t = gid >> 8;
    int c = gid & 255;
    float w0 = top_w[2*t];
    float w1 = top_w[2*t + 1];
    const float4* p0a = (const float4*)(y0 + (size_t)(2*t) * D_MODEL);
    const float4* p0b = (const float4*)(y1 + (size_t)(2*t) * D_MODEL);
    const float4* p1a = (const float4*)(y0 + (size_t)(2*t + 1) * D_MODEL);
    const float4* p1b = (const float4*)(y1 + (size_t)(2*t + 1) * D_MODEL);
    float4 a0 = p0a[c], a1 = p0b[c];
    float4 b0 = p1a[c], b1 = p1b[c];
    float4 o;
    o.x = w0*(a0.x + a1.x) + w1*(b0.x + b1.x);
    o.y = w0*(a0.y + a1.y) + w1*(b0.y + b1.y);
    o.z = w0*(a0.z + a1.z) + w1*(b0.z + b1.z);
    o.w = w0*(a0.w + a1.w) + w1*(b0.w + b1.w);
    ((float4*)out)[gid] = o;
}

// ---------------------------------------------------------------- launch
extern "C" void kernel_launch(void* const* d_in, const int* in_sizes, int n_in,
                              void* d_out, int out_size, void* d_ws, size_t ws_size,
                              hipStream_t stream)
{
    const float* x  = (const float*)d_in[0];
    const float* Wg = (const float*)d_in[1];
    const float* W1 = (const float*)d_in[2];
    const float* b1 = (const float*)d_in[3];
    const float* W2 = (const float*)d_in[4];
    const float* b2 = (const float*)d_in[5];
    float* out = (float*)d_out;

    char* ws = (char*)d_ws;
    size_t off = 0;
    int*   top_e   = (int*)(ws + off);  off += (size_t)NPAIR * 4;
    float* top_w   = (float*)(ws + off); off += (size_t)NPAIR * 4;
    int*   offsets = (int*)(ws + off);  off += 256;
    int*   pair_id = (int*)(ws + off);  off += (size_t)NPAIR * 4;
    off = (off + 255) & ~(size_t)255;
    __hip_bfloat16* xb  = (__hip_bfloat16*)(ws + off); off += (size_t)T_TOK * D_MODEL * 2;
    __hip_bfloat16* W1T = (__hip_bfloat16*)(ws + off); off += (size_t)N_EXPERTS * D_MODEL * D_FF * 2;
    __hip_bfloat16* W2T = (__hip_bfloat16*)(ws + off); off += (size_t)N_EXPERTS * D_MODEL * D_FF * 2;
    __hip_bfloat16* h   = (__hip_bfloat16*)(ws + off); off += (size_t)NPAIR * D_FF * 2;
    float*          y   = (float*)(ws + off);          off += (size_t)NPAIR * D_MODEL * 4;

    // split-K partial #1 overlays W1T (dead after gemm1; 64 MiB >= 32 MiB needed).
    float* ypart = (float*)W1T;

    router_kernel<<<T_TOK / 4, 256, 0, stream>>>(x, Wg, top_e, top_w, xb);
    setup_kernel<<<1, 256, 0, stream>>>(top_e, offsets, pair_id);

    transpose_cast_kernel<<<dim3(D_FF / 64, D_MODEL / 64, N_EXPERTS), 256, 0, stream>>>(
        W1, W1T, D_MODEL, D_FF);
    transpose_cast_kernel<<<dim3(D_MODEL / 64, D_FF / 64, N_EXPERTS), 256, 0, stream>>>(
        W2, W2T, D_FF, D_MODEL);

    // XCD-pinned flat grids: bid & 7 == expert (grid % 8 == 0 keeps the map exact)
    gemm1_mfma<<<N_EXPERTS * MT_MAX * (D_FF / 128), 256, 0, stream>>>(
        xb, W1T, b1, offsets, pair_id, h);
    gemm2_mfma<<<N_EXPERTS * MT_MAX * (D_MODEL / 128) * KSPLIT, 256, 0, stream>>>(
        h, W2T, b2, offsets, pair_id, y, ypart);
    combine_kernel<<<T_TOK, 256, 0, stream>>>(y, ypart, top_w, out);
}

// Round 5
// 648.206 us; speedup vs baseline: 1.1808x; 1.1808x over previous
//
#include <hip/hip_runtime.h>
#include <hip/hip_bf16.h>

#define D_MODEL 1024
#define D_FF    4096
#define N_EXPERTS 8
#define TOPK    2
#define T_TOK   4096
#define NPAIR   (T_TOK * TOPK)   // 8192
#define MT_MAX  32               // ceil(T_TOK / 128) worst case per expert
#define KSPLIT  2                // gemm2 split-K factor

typedef __attribute__((ext_vector_type(8))) short s8v;          // bf16x8 MFMA frag
typedef __attribute__((ext_vector_type(4))) float f4v;          // fp32x4 MFMA acc
typedef __attribute__((ext_vector_type(4))) unsigned short u16x4;
typedef __attribute__((ext_vector_type(8))) unsigned short u16x8;

__device__ __forceinline__ void async16(const void* g, void* l) {
    __builtin_amdgcn_global_load_lds(
        (const __attribute__((address_space(1))) void*)g,
        (__attribute__((address_space(3))) void*)l, 16, 0, 0);
}

__device__ __forceinline__ float gelu_tanh(float v) {
    float u = 0.7978845608028654f * (v + 0.044715f * v * v * v);
    float t = 1.0f - 2.0f / (1.0f + __expf(2.0f * u));
    return 0.5f * v * (1.0f + t);
}

__device__ __forceinline__ unsigned short f2bf(float f) {
    union { __hip_bfloat16 b; unsigned short u; } cv;
    cv.b = __float2bfloat16(f);
    return cv.u;
}

// ---------------------------------------------------------------- router (+x cast)
__global__ __launch_bounds__(256) void router_kernel(
    const float* __restrict__ x, const float* __restrict__ Wg,
    int* __restrict__ top_e, float* __restrict__ top_w,
    __hip_bfloat16* __restrict__ xb)
{
    int wave = threadIdx.x >> 6;
    int lane = threadIdx.x & 63;
    int t = blockIdx.x * 4 + wave;
    if (t >= T_TOK) return;

    float acc[8] = {0.f,0.f,0.f,0.f,0.f,0.f,0.f,0.f};
    const float* xr = x + (size_t)t * D_MODEL;
    unsigned short* xbr = (unsigned short*)xb + (size_t)t * D_MODEL;
    #pragma unroll
    for (int it = 0; it < 4; it++) {
        int d0 = it * 256 + lane * 4;
        float4 xv = *(const float4*)(xr + d0);
        unsigned short bfv[4] = {f2bf(xv.x), f2bf(xv.y), f2bf(xv.z), f2bf(xv.w)};
        *(u16x4*)(xbr + d0) = *(u16x4*)bfv;
        float xa[4] = {xv.x, xv.y, xv.z, xv.w};
        #pragma unroll
        for (int u = 0; u < 4; u++) {
            const float* wr = Wg + (size_t)(d0 + u) * N_EXPERTS;
            float4 w0 = *(const float4*)wr;
            float4 w1 = *(const float4*)(wr + 4);
            acc[0] += xa[u] * w0.x; acc[1] += xa[u] * w0.y;
            acc[2] += xa[u] * w0.z; acc[3] += xa[u] * w0.w;
            acc[4] += xa[u] * w1.x; acc[5] += xa[u] * w1.y;
            acc[6] += xa[u] * w1.z; acc[7] += xa[u] * w1.w;
        }
    }
    #pragma unroll
    for (int off = 32; off >= 1; off >>= 1) {
        #pragma unroll
        for (int e = 0; e < 8; e++) acc[e] += __shfl_xor(acc[e], off);
    }
    if (lane == 0) {
        float m = acc[0];
        #pragma unroll
        for (int e = 1; e < 8; e++) m = fmaxf(m, acc[e]);
        float p[8]; float s = 0.f;
        #pragma unroll
        for (int e = 0; e < 8; e++) { p[e] = expf(acc[e] - m); s += p[e]; }
        float inv = 1.f / s;
        #pragma unroll
        for (int e = 0; e < 8; e++) p[e] *= inv;
        int i0 = 0; float b0 = p[0];
        #pragma unroll
        for (int e = 1; e < 8; e++) if (p[e] > b0) { b0 = p[e]; i0 = e; }
        int i1 = -1; float b1 = -1.f;
        #pragma unroll
        for (int e = 0; e < 8; e++) if (e != i0 && p[e] > b1) { b1 = p[e]; i1 = e; }
        top_e[2*t]   = i0; top_w[2*t]   = b0;
        top_e[2*t+1] = i1; top_w[2*t+1] = b1;
    }
}

// ------------------------------------------- setup: histogram + offsets + scatter
__global__ __launch_bounds__(256) void setup_kernel(
    const int* __restrict__ top_e, int* __restrict__ offsets,
    int* __restrict__ pair_id)
{
    __shared__ int cnt[N_EXPERTS], base[N_EXPERTS], cur[N_EXPERTS];
    int tid = threadIdx.x;
    if (tid < N_EXPERTS) { cnt[tid] = 0; cur[tid] = 0; }
    __syncthreads();
    for (int i = tid; i < NPAIR; i += 256) atomicAdd(&cnt[top_e[i]], 1);
    __syncthreads();
    if (tid == 0) {
        int run = 0;
        #pragma unroll
        for (int e = 0; e < N_EXPERTS; e++) { base[e] = run; offsets[e] = run; run += cnt[e]; }
        offsets[N_EXPERTS] = run;
    }
    __syncthreads();
    for (int i = tid; i < NPAIR; i += 256) {
        int e = top_e[i];
        int pos = atomicAdd(&cur[e], 1);
        pair_id[base[e] + pos] = i;
    }
}

// ------------------------------------------------- transpose-cast W -> [E][N][K] bf16
__global__ __launch_bounds__(256) void transpose_cast_kernel(
    const float* __restrict__ src, __hip_bfloat16* __restrict__ dst, int R, int C)
{
    int e = blockIdx.z;
    src += (size_t)e * R * C;
    dst += (size_t)e * R * C;
    int b0 = blockIdx.x * 64;
    int a0 = blockIdx.y * 64;

    __shared__ float tile[64][65];
    int tid = threadIdx.x;
    int lr = tid >> 4;
    int lc = (tid & 15) * 4;
    #pragma unroll
    for (int rr = 0; rr < 4; rr++) {
        int r = lr + rr * 16;
        *(float4*)&tile[r][lc] = *(const float4*)(src + (size_t)(a0 + r) * C + b0 + lc);
    }
    __syncthreads();
    int oc = tid >> 3;
    int oj = (tid & 7) * 8;
    #pragma unroll
    for (int rr = 0; rr < 2; rr++) {
        int c = oc + rr * 32;
        unsigned short t[8];
        #pragma unroll
        for (int j = 0; j < 8; j++) t[j] = f2bf(tile[oj + j][c]);
        *(u16x8*)((unsigned short*)dst + (size_t)(b0 + c) * R + a0 + oj) = *(u16x8*)t;
    }
}

// ---------------------------------------------------------------- GEMM1 (MFMA)
// 128x128 tile, BK=64 (halved K-step count, full-cache-line staging runs).
// Staging chunk map (swizzled on the GLOBAL side, LDS linear per m104/m173):
//   chunk c (16B): row R = c>>3, stored k-chunk kcs = c&7,
//   global k-chunk kc = kcs ^ (R&7)   [T2-style XOR so reads are conflict-free]
//   thread tid owns chunks {tid + 256u}: R_u = (tid>>3)+32u, kc = (tid&7)^((tid>>3)&7)
//   -> per wave-op: 8 consecutive rows x 128B full-line contiguous runs.
// Fragment read (lane l, region rb+i, k-subtile t):
//   As + (rb+i)*1024 + (l&15)*64 + (((t*4)+(l>>4)) ^ (l&7))*8   (2-way banks = free)
__global__ __launch_bounds__(256) void gemm1_mfma(
    const __hip_bfloat16* __restrict__ xb, const __hip_bfloat16* __restrict__ W1T,
    const float* __restrict__ b1,
    const int* __restrict__ offsets, const int* __restrict__ pair_id,
    __hip_bfloat16* __restrict__ h)
{
    int e  = blockIdx.y >> 5;
    int mt = blockIdx.y & 31;
    int off_e = offsets[e];
    int cnt   = offsets[e + 1] - off_e;
    int m0 = mt * 128;
    if (m0 >= cnt) return;
    int n0 = blockIdx.x * 128;

    __shared__ __hip_bfloat16 As[128 * 64];
    __shared__ __hip_bfloat16 Bs[128 * 64];
    __shared__ int pid[128];

    int tid = threadIdx.x;
    if (tid < 128) {
        int r = m0 + tid; if (r >= cnt) r = cnt - 1;
        pid[tid] = pair_id[off_e + r];
    }
    __syncthreads();

    int lane = tid & 63, wid = tid >> 6;

    // staging geometry
    int Rb = tid >> 3;                               // base row (chunk tid)
    int kc = (tid & 7) ^ ((tid >> 3) & 7);           // global k-chunk (same for all u)
    const __hip_bfloat16* WT = W1T + (size_t)e * (D_MODEL * D_FF);
    const __hip_bfloat16* gA[4];
    const __hip_bfloat16* gB[4];
    #pragma unroll
    for (int u = 0; u < 4; u++) {
        int R = Rb + 32 * u;
        gA[u] = xb + (size_t)(pid[R] >> 1) * D_MODEL + kc * 8;
        gB[u] = WT + (size_t)(n0 + R) * D_MODEL + kc * 8;
    }

    // fragment-read offsets
    int fm = lane & 15;
    int wm = (wid >> 1) * 64;
    int wn = (wid & 1) * 64;
    int rba = (wid >> 1) * 4;
    int rbb = (wid & 1) * 4;
    int rowoff = (lane & 15) * 64;
    int x0 = (((lane >> 4)    ) ^ (lane & 7)) * 8;   // k-subtile 0
    int x1 = (((lane >> 4) + 4) ^ (lane & 7)) * 8;   // k-subtile 1

    f4v acc[4][4];
    #pragma unroll
    for (int i = 0; i < 4; i++)
        #pragma unroll
        for (int j = 0; j < 4; j++)
            acc[i][j] = (f4v){0.f, 0.f, 0.f, 0.f};

    for (int k0 = 0; k0 < D_MODEL; k0 += 64) {
        #pragma unroll
        for (int u = 0; u < 4; u++) {
            async16(gA[u] + k0, As + (tid + 256 * u) * 8);
            async16(gB[u] + k0, Bs + (tid + 256 * u) * 8);
        }
        __syncthreads();
        // k-subtile 0
        {
            s8v af[4], bfr[4];
            #pragma unroll
            for (int i = 0; i < 4; i++)
                af[i] = *(const s8v*)(As + (rba + i) * 1024 + rowoff + x0);
            #pragma unroll
            for (int j = 0; j < 4; j++)
                bfr[j] = *(const s8v*)(Bs + (rbb + j) * 1024 + rowoff + x0);
            #pragma unroll
            for (int i = 0; i < 4; i++)
                #pragma unroll
                for (int j = 0; j < 4; j++)
                    acc[i][j] = __builtin_amdgcn_mfma_f32_16x16x32_bf16(af[i], bfr[j], acc[i][j], 0, 0, 0);
        }
        // k-subtile 1
        {
            s8v af[4], bfr[4];
            #pragma unroll
            for (int i = 0; i < 4; i++)
                af[i] = *(const s8v*)(As + (rba + i) * 1024 + rowoff + x1);
            #pragma unroll
            for (int j = 0; j < 4; j++)
                bfr[j] = *(const s8v*)(Bs + (rbb + j) * 1024 + rowoff + x1);
            #pragma unroll
            for (int i = 0; i < 4; i++)
                #pragma unroll
                for (int j = 0; j < 4; j++)
                    acc[i][j] = __builtin_amdgcn_mfma_f32_16x16x32_bf16(af[i], bfr[j], acc[i][j], 0, 0, 0);
        }
        __syncthreads();
    }

    int rq = (lane >> 4) * 4;   // C/D: row = (lane>>4)*4 + reg, col = lane&15
    #pragma unroll
    for (int i = 0; i < 4; i++) {
        #pragma unroll
        for (int j = 0; j < 4; j++) {
            int n = n0 + wn + j * 16 + fm;
            float bias = b1[e * D_FF + n];
            #pragma unroll
            for (int r = 0; r < 4; r++) {
                int m = wm + i * 16 + rq + r;
                if (m0 + m < cnt) {
                    float v = acc[i][j][r] + bias;
                    h[(size_t)(off_e + m0 + m) * D_FF + n] = __float2bfloat16(gelu_tanh(v));
                }
            }
        }
    }
}

// ---------------------------------------------------------------- GEMM2 (MFMA, split-K)
// Same BK=64 structure. blockIdx.z = K-split: split s covers [s*2048, +2048).
// Split 0 adds bias -> y0; split 1 -> y1 (overlaid on dead W1T). combine folds.
__global__ __launch_bounds__(256) void gemm2_mfma(
    const __hip_bfloat16* __restrict__ h, const __hip_bfloat16* __restrict__ W2T,
    const float* __restrict__ b2,
    const int* __restrict__ offsets, const int* __restrict__ pair_id,
    float* __restrict__ y0, float* __restrict__ y1)
{
    int e  = blockIdx.y >> 5;
    int mt = blockIdx.y & 31;
    int split = blockIdx.z;
    int off_e = offsets[e];
    int cnt   = offsets[e + 1] - off_e;
    int m0 = mt * 128;
    if (m0 >= cnt) return;
    int n0 = blockIdx.x * 128;

    __shared__ __hip_bfloat16 As[128 * 64];
    __shared__ __hip_bfloat16 Bs[128 * 64];
    __shared__ int pid[128];

    int tid = threadIdx.x;
    if (tid < 128) {
        int r = m0 + tid; if (r >= cnt) r = cnt - 1;
        pid[tid] = pair_id[off_e + r];
    }
    __syncthreads();

    int lane = tid & 63, wid = tid >> 6;

    const int KS = D_FF / KSPLIT;          // 2048
    int kbase = split * KS;

    int Rb = tid >> 3;
    int kc = (tid & 7) ^ ((tid >> 3) & 7);
    const __hip_bfloat16* WT = W2T + (size_t)e * (D_FF * D_MODEL);
    const __hip_bfloat16* gA[4];
    const __hip_bfloat16* gB[4];
    #pragma unroll
    for (int u = 0; u < 4; u++) {
        int R = Rb + 32 * u;
        int mr = m0 + R; if (mr >= cnt) mr = cnt - 1;
        gA[u] = h + (size_t)(off_e + mr) * D_FF + kbase + kc * 8;
        gB[u] = WT + (size_t)(n0 + R) * D_FF + kbase + kc * 8;
    }

    int fm = lane & 15;
    int wm = (wid >> 1) * 64;
    int wn = (wid & 1) * 64;
    int rba = (wid >> 1) * 4;
    int rbb = (wid & 1) * 4;
    int rowoff = (lane & 15) * 64;
    int x0 = (((lane >> 4)    ) ^ (lane & 7)) * 8;
    int x1 = (((lane >> 4) + 4) ^ (lane & 7)) * 8;

    f4v acc[4][4];
    #pragma unroll
    for (int i = 0; i < 4; i++)
        #pragma unroll
        for (int j = 0; j < 4; j++)
            acc[i][j] = (f4v){0.f, 0.f, 0.f, 0.f};

    for (int k0 = 0; k0 < KS; k0 += 64) {
        #pragma unroll
        for (int u = 0; u < 4; u++) {
            async16(gA[u] + k0, As + (tid + 256 * u) * 8);
            async16(gB[u] + k0, Bs + (tid + 256 * u) * 8);
        }
        __syncthreads();
        {
            s8v af[4], bfr[4];
            #pragma unroll
            for (int i = 0; i < 4; i++)
                af[i] = *(const s8v*)(As + (rba + i) * 1024 + rowoff + x0);
            #pragma unroll
            for (int j = 0; j < 4; j++)
                bfr[j] = *(const s8v*)(Bs + (rbb + j) * 1024 + rowoff + x0);
            #pragma unroll
            for (int i = 0; i < 4; i++)
                #pragma unroll
                for (int j = 0; j < 4; j++)
                    acc[i][j] = __builtin_amdgcn_mfma_f32_16x16x32_bf16(af[i], bfr[j], acc[i][j], 0, 0, 0);
        }
        {
            s8v af[4], bfr[4];
            #pragma unroll
            for (int i = 0; i < 4; i++)
                af[i] = *(const s8v*)(As + (rba + i) * 1024 + rowoff + x1);
            #pragma unroll
            for (int j = 0; j < 4; j++)
                bfr[j] = *(const s8v*)(Bs + (rbb + j) * 1024 + rowoff + x1);
            #pragma unroll
            for (int i = 0; i < 4; i++)
                #pragma unroll
                for (int j = 0; j < 4; j++)
                    acc[i][j] = __builtin_amdgcn_mfma_f32_16x16x32_bf16(af[i], bfr[j], acc[i][j], 0, 0, 0);
        }
        __syncthreads();
    }

    float* yo = split ? y1 : y0;
    int rq = (lane >> 4) * 4;
    #pragma unroll
    for (int i = 0; i < 4; i++) {
        #pragma unroll
        for (int j = 0; j < 4; j++) {
            int n = n0 + wn + j * 16 + fm;
            float bias = split ? 0.f : b2[e * D_MODEL + n];
            #pragma unroll
            for (int r = 0; r < 4; r++) {
                int m = wm + i * 16 + rq + r;
                if (m0 + m < cnt) {
                    int p = pid[m];
                    yo[(size_t)p * D_MODEL + n] = acc[i][j][r] + bias;
                }
            }
        }
    }
}

// ---------------------------------------------------------------- combine
__global__ __launch_bounds__(256) void combine_kernel(
    const float* __restrict__ y0, const float* __restrict__ y1,
    const float* __restrict__ top_w, float* __restrict__ out)
{
    int gid = blockIdx.x * blockDim.x + threadIdx.x;
    int t = gid >> 8;
    int c = gid & 255;
    float w0 = top_w[2*t];
    float w1 = top_w[2*t + 1];
    const float4* p0a = (const float4*)(y0 + (size_t)(2*t) * D_MODEL);
    const float4* p0b = (const float4*)(y1 + (size_t)(2*t) * D_MODEL);
    const float4* p1a = (const float4*)(y0 + (size_t)(2*t + 1) * D_MODEL);
    const float4* p1b = (const float4*)(y1 + (size_t)(2*t + 1) * D_MODEL);
    float4 a0 = p0a[c], a1 = p0b[c];
    float4 b0 = p1a[c], b1 = p1b[c];
    float4 o;
    o.x = w0*(a0.x + a1.x) + w1*(b0.x + b1.x);
    o.y = w0*(a0.y + a1.y) + w1*(b0.y + b1.y);
    o.z = w0*(a0.z + a1.z) + w1*(b0.z + b1.z);
    o.w = w0*(a0.w + a1.w) + w1*(b0.w + b1.w);
    ((float4*)out)[gid] = o;
}

// ---------------------------------------------------------------- launch
extern "C" void kernel_launch(void* const* d_in, const int* in_sizes, int n_in,
                              void* d_out, int out_size, void* d_ws, size_t ws_size,
                              hipStream_t stream)
{
    const float* x  = (const float*)d_in[0];
    const float* Wg = (const float*)d_in[1];
    const float* W1 = (const float*)d_in[2];
    const float* b1 = (const float*)d_in[3];
    const float* W2 = (const float*)d_in[4];
    const float* b2 = (const float*)d_in[5];
    float* out = (float*)d_out;

    char* ws = (char*)d_ws;
    size_t off = 0;
    int*   top_e   = (int*)(ws + off);  off += (size_t)NPAIR * 4;
    float* top_w   = (float*)(ws + off); off += (size_t)NPAIR * 4;
    int*   offsets = (int*)(ws + off);  off += 256;
    int*   pair_id = (int*)(ws + off);  off += (size_t)NPAIR * 4;
    off = (off + 255) & ~(size_t)255;
    __hip_bfloat16* xb  = (__hip_bfloat16*)(ws + off); off += (size_t)T_TOK * D_MODEL * 2;
    __hip_bfloat16* W1T = (__hip_bfloat16*)(ws + off); off += (size_t)N_EXPERTS * D_MODEL * D_FF * 2;
    __hip_bfloat16* W2T = (__hip_bfloat16*)(ws + off); off += (size_t)N_EXPERTS * D_MODEL * D_FF * 2;
    __hip_bfloat16* h   = (__hip_bfloat16*)(ws + off); off += (size_t)NPAIR * D_FF * 2;
    float*          y   = (float*)(ws + off);          off += (size_t)NPAIR * D_MODEL * 4;

    // split-K partial #1 overlays W1T (dead after gemm1; 64 MiB >= 32 MiB needed).
    float* ypart = (float*)W1T;

    router_kernel<<<T_TOK / 4, 256, 0, stream>>>(x, Wg, top_e, top_w, xb);
    setup_kernel<<<1, 256, 0, stream>>>(top_e, offsets, pair_id);

    transpose_cast_kernel<<<dim3(D_FF / 64, D_MODEL / 64, N_EXPERTS), 256, 0, stream>>>(
        W1, W1T, D_MODEL, D_FF);
    transpose_cast_kernel<<<dim3(D_MODEL / 64, D_FF / 64, N_EXPERTS), 256, 0, stream>>>(
        W2, W2T, D_FF, D_MODEL);

    gemm1_mfma<<<dim3(D_FF / 128, N_EXPERTS * MT_MAX), 256, 0, stream>>>(
        xb, W1T, b1, offsets, pair_id, h);
    gemm2_mfma<<<dim3(D_MODEL / 128, N_EXPERTS * MT_MAX, KSPLIT), 256, 0, stream>>>(
        h, W2T, b2, offsets, pair_id, y, ypart);
    combine_kernel<<<T_TOK, 256, 0, stream>>>(y, ypart, top_w, out);
}